// Round 15
// baseline (300.904 us; speedup 1.0000x reference)
//
#include <hip/hip_runtime.h>
#include <hip/hip_cooperative_groups.h>
#include <stdint.h>

namespace cg = cooperative_groups;

#define H 512
#define BATCH 64
#define NIN 256
#define NOUT 128
#define TTOT 1000
#define CHL 20
#define NCH 50
#define NBLK 512

typedef __attribute__((ext_vector_type(4))) float f32x4;

// pack 4 f32 -> 4 fp8 e4m3 (OCP) bytes
static __device__ __forceinline__ int pk_fp8x4(float a, float b, float c,
                                               float d) {
  int v = 0;
  v = __builtin_amdgcn_cvt_pk_fp8_f32(a, b, v, false);  // bytes 0,1
  v = __builtin_amdgcn_cvt_pk_fp8_f32(c, d, v, true);   // bytes 2,3
  return v;
}
__device__ __forceinline__ void gload_lds16(const void* g, void* l) {
  __builtin_amdgcn_global_load_lds(
      (const __attribute__((address_space(1))) uint32_t*)g,
      (__attribute__((address_space(3))) uint32_t*)l, 16, 0, 0);
}

__global__ __launch_bounds__(256, 4) void k_mega(
    const float* __restrict__ x, const float* __restrict__ Win,
    const float* __restrict__ Wrec, const float* __restrict__ Wout,
    float* __restrict__ out, uint8_t* __restrict__ y,
    uint8_t* __restrict__ Winb, float* __restrict__ Bc,
    float* __restrict__ Vst, int* __restrict__ flags) {
  cg::grid_group grid = cg::this_grid();
  __shared__ __align__(16) char sm[32768];
  const int bid = blockIdx.x;
  const int tid = threadIdx.x;
  const int wave = tid >> 6;
  const int l = tid & 63;

  // ============ phase 1: IIR filter (x -> y fp8) + Win -> fp8 cast =========
  for (int v = bid; v < 1664; v += NBLK) {
    if (v < 1600) {
      float4* y9dep = (float4*)sm;  // [2][64]
      const int c = v >> 5;             // 50 chunks
      const int bp = v & 31;            // 32 batch pairs
      const int ig = tid & 63;          // 64 groups of 4 floats
      const int hf = (tid >> 6) & 1;    // time half
      const int bo = tid >> 7;          // batch within pair
      const int b = bp * 2 + bo;
      const size_t base = ((size_t)(c * CHL) * 64 + b) * 256 + ig * 4;
      const float* xa = x + base + (size_t)hf * 10 * 16384;
      uint8_t* ya = y + base + (size_t)hf * 10 * 16384;
      float4 p[10];
      float ax = 0.f, ay = 0.f, az = 0.f, aw = 0.f;
#pragma unroll
      for (int s = 0; s < 10; ++s) {
        float4 xv = *(const float4*)(xa + (size_t)s * 16384);
        ax = 0.95f * ax + xv.x; ay = 0.95f * ay + xv.y;
        az = 0.95f * az + xv.z; aw = 0.95f * aw + xv.w;
        p[s] = make_float4(ax, ay, az, aw);
        if (hf == 0)
          *(int*)(ya + (size_t)s * 16384) = pk_fp8x4(ax, ay, az, aw);
      }
      if (hf == 0) y9dep[bo * 64 + ig] = make_float4(ax, ay, az, aw);
      __syncthreads();
      if (hf == 1) {
        const float4 y9 = y9dep[bo * 64 + ig];
        const float pw[10] = {0.95f, 0.9025f, 0.857375f, 0.81450625f,
                              0.7737809375f, 0.735091890625f,
                              0.69833729609375f, 0.6634204312890625f,
                              0.6302494097246094f, 0.5987369392383789f};
#pragma unroll
        for (int s = 0; s < 10; ++s) {
          const float ox = p[s].x + pw[s] * y9.x;
          const float oy = p[s].y + pw[s] * y9.y;
          const float oz = p[s].z + pw[s] * y9.z;
          const float ow = p[s].w + pw[s] * y9.w;
          *(int*)(ya + (size_t)s * 16384) = pk_fp8x4(ox, oy, oz, ow);
        }
      }
      __syncthreads();  // y9dep reused next virt iteration
    } else {
      const int g = (v - 1600) * 256 + tid;  // 16384 thr x 8 = 512*256
      const float4* ptr = (const float4*)Win + (size_t)g * 2;
      float4 a = ptr[0], b = ptr[1];
      int2 o;
      o.x = pk_fp8x4(a.x, a.y, a.z, a.w);
      o.y = pk_fp8x4(b.x, b.y, b.z, b.w);
      *(int2*)(Winb + (size_t)g * 8) = o;
    }
  }
  grid.sync();

  // ============ phase 2: bc — Bc[(c*64+b),h] = 0.5*(Win.y19) - 60*(1-a^20) ==
  // BK=128 two-stage (32 KB LDS), A rows gathered from y's s=19 rows.
  if (bid < 100) {
    char* ldsA = sm;          // 128 x 128 B
    char* ldsB = sm + 16384;  // 128 x 128 B
    const int bn = bid & 3;
    const int bm = bid >> 2;  // 25 M-tiles (3200 rows)
    const int wr = wave >> 1, wc = wave & 1;
    const int fr = l & 15, fq = l >> 4;
    const char* Bb = (const char*)Winb + (size_t)bn * 128 * 256;
    const int srow = l >> 3;
    const int scol = (((l & 7) ^ srow) << 4);
    f32x4 acc[4][4] = {};
#pragma unroll
    for (int ks = 0; ks < 2; ++ks) {
      const int kb = ks * 128;
#pragma unroll
      for (int i = 0; i < 4; ++i) {
        const int q = wave * 4 + i;
        const int row = q * 8 + srow;
        const int vr = bm * 128 + row;  // virtual yend row -> (chunk, batch)
        const int cc = vr >> 6, bb2 = vr & 63;
        gload_lds16((const char*)y +
                        ((size_t)(cc * CHL + CHL - 1) * 64 + bb2) * 256 + kb + scol,
                    ldsA + q * 1024);
        gload_lds16(Bb + (size_t)row * 256 + kb + scol, ldsB + q * 1024);
      }
      __syncthreads();
#pragma unroll
      for (int kk = 0; kk < 4; ++kk) {
        const int cb = kk * 32 + fq * 8;
        long a[4], b[4];
#pragma unroll
        for (int m = 0; m < 4; ++m) {
          const int row = wr * 64 + m * 16 + fr;
          a[m] = *(const long*)(ldsA + row * 128 + (cb ^ ((row & 7) << 4)));
        }
#pragma unroll
        for (int n = 0; n < 4; ++n) {
          const int row = wc * 64 + n * 16 + fr;
          b[n] = *(const long*)(ldsB + row * 128 + (cb ^ ((row & 7) << 4)));
        }
#pragma unroll
        for (int m = 0; m < 4; ++m)
#pragma unroll
          for (int n = 0; n < 4; ++n)
            acc[m][n] = __builtin_amdgcn_mfma_f32_16x16x32_fp8_fp8(
                a[m], b[n], acc[m][n], 0, 0, 0);
      }
      __syncthreads();
    }
#pragma unroll
    for (int m = 0; m < 4; ++m) {
      const int r0 = bm * 128 + wr * 64 + m * 16 + fq * 4;
#pragma unroll
      for (int n = 0; n < 4; ++n) {
        const int col = bn * 128 + wc * 64 + n * 16 + fr;
        f32x4 a = acc[m][n];
#pragma unroll
        for (int j = 0; j < 4; ++j)
          Bc[(size_t)(r0 + j) * 512 + col] = 0.5f * a[j] - 38.4908446554876f;
      }
    }
  }
  grid.sync();

  // ============ phase 3: compose Vst + zero out + zero flags ================
  if (bid < 128) {
    const int idx = bid * 256 + tid;        // 32768 = 64b*512h
    const float AL = 0.35848592240854223f;  // 0.95^20
    float vv = -60.f;
#pragma unroll
    for (int c = 0; c < NCH; c += 5) {
      float b0 = Bc[(size_t)(c + 0) * 32768 + idx];
      float b1 = Bc[(size_t)(c + 1) * 32768 + idx];
      float b2 = Bc[(size_t)(c + 2) * 32768 + idx];
      float b3 = Bc[(size_t)(c + 3) * 32768 + idx];
      float b4 = Bc[(size_t)(c + 4) * 32768 + idx];
      Vst[(size_t)(c + 0) * 32768 + idx] = vv; vv = AL * vv + b0;
      Vst[(size_t)(c + 1) * 32768 + idx] = vv; vv = AL * vv + b1;
      Vst[(size_t)(c + 2) * 32768 + idx] = vv; vv = AL * vv + b2;
      Vst[(size_t)(c + 3) * 32768 + idx] = vv; vv = AL * vv + b3;
      Vst[(size_t)(c + 4) * 32768 + idx] = vv; vv = AL * vv + b4;
    }
  } else if (bid == 128) {  // zero out (64x128 floats = 2048 float4)
    float4 z = make_float4(0.f, 0.f, 0.f, 0.f);
    float4* o = (float4*)out + tid;
#pragma unroll
    for (int i = 0; i < 8; ++i) o[i * 256] = z;
  } else if (bid == 129) {
    if (tid < BATCH) flags[tid] = 0;
  }
  grid.sync();

  // ============ phase 4: screen — fp8 GEMM y.Win^T + threshold epilogue =====
  // grid-stride over 2000 tiles with XCD swizzle (512 % 8 == 0 keeps
  // same-A tiles on one XCD). v(t) >= -45.5 <=> acc >= 29 - 2*As*(v0+60).
  for (int v = bid; v < 2000; v += NBLK) {
    char* ldsA = sm;          // 128 x 128 B
    char* ldsB = sm + 16384;  // 128 x 128 B
    const int wg = (v & 7) * 250 + (v >> 3);
    const int bn = wg & 3;
    const int bm = wg >> 2;  // 500 M-tiles
    const int wr = wave >> 1, wc = wave & 1;
    const int fr = l & 15, fq = l >> 4;
    const char* Ab = (const char*)y + (size_t)bm * 128 * 256;
    const char* Bb = (const char*)Winb + (size_t)bn * 128 * 256;
    const int srow = l >> 3;
    const int scol = (((l & 7) ^ srow) << 4);
    f32x4 acc[4][4] = {};
#pragma unroll
    for (int ks = 0; ks < 2; ++ks) {
      const int kb = ks * 128;
#pragma unroll
      for (int i = 0; i < 4; ++i) {
        const int q = wave * 4 + i;
        const int row = q * 8 + srow;
        gload_lds16(Ab + (size_t)row * 256 + kb + scol, ldsA + q * 1024);
        gload_lds16(Bb + (size_t)row * 256 + kb + scol, ldsB + q * 1024);
      }
      __syncthreads();
#pragma unroll
      for (int kk = 0; kk < 4; ++kk) {
        const int cb = kk * 32 + fq * 8;
        long a[4], b[4];
#pragma unroll
        for (int m = 0; m < 4; ++m) {
          const int row = wr * 64 + m * 16 + fr;
          a[m] = *(const long*)(ldsA + row * 128 + (cb ^ ((row & 7) << 4)));
        }
#pragma unroll
        for (int n = 0; n < 4; ++n) {
          const int row = wc * 64 + n * 16 + fr;
          b[n] = *(const long*)(ldsB + row * 128 + (cb ^ ((row & 7) << 4)));
        }
#pragma unroll
        for (int m = 0; m < 4; ++m)
#pragma unroll
          for (int n = 0; n < 4; ++n)
            acc[m][n] = __builtin_amdgcn_mfma_f32_16x16x32_fp8_fp8(
                a[m], b[n], acc[m][n], 0, 0, 0);
      }
      __syncthreads();
    }
    // epilogue: stage block-uniform Vst slice (64 b x 128 h = 32 KB) over sm
    const int c = (bm * 2) / CHL;           // block-uniform (CHL even)
    const int s = (bm * 2 + wr) - c * CHL;  // wave-uniform
    float* ldsV = (float*)sm;
    {
      const float* vsrc = Vst + ((size_t)c * 64) * 512 + bn * 128;
      const int vrow = l >> 5;
      const int vcol = (l & 31) * 4;
#pragma unroll
      for (int i = 0; i < 8; ++i) {
        const int brow = (wave * 8 + i) * 2 + vrow;
        gload_lds16(vsrc + (size_t)brow * 512 + vcol,
                    ldsV + (wave * 8 + i) * 256);
      }
    }
    __syncthreads();
    const float As = exp2f(-(float)(s + 1) * 0.07400058144086257f);
    unsigned int cmask = 0;
#pragma unroll
    for (int m = 0; m < 4; ++m) {
#pragma unroll
      for (int j = 0; j < 4; ++j) {
        const int b = m * 16 + fq * 4 + j;
        bool cb2 = false;
#pragma unroll
        for (int n = 0; n < 4; ++n) {
          const int hl = wc * 64 + n * 16 + fr;
          const float th = 29.f - 2.f * As * (ldsV[b * 128 + hl] + 60.f);
          cb2 |= (acc[m][n][j] >= th);
        }
        cmask |= cb2 ? (1u << (m * 4 + j)) : 0u;
      }
    }
    if (__ballot(cmask != 0u)) {  // never taken when screen is clean
#pragma unroll
      for (int m = 0; m < 4; ++m)
#pragma unroll
        for (int j = 0; j < 4; ++j)
          if (cmask & (1u << (m * 4 + j))) flags[m * 16 + fq * 4 + j] = 1;
    }
    __syncthreads();  // ldsV reads done before next v's stage
  }
  grid.sync();

  // ============ phase 5: exact fallback (2 neurons/thread; never taken) =====
  if (bid < 64 && flags[bid]) {
    const int b = bid;
    float* xr = (float*)sm;                                       // 256 f32
    unsigned long long* wbal = (unsigned long long*)(sm + 1024);  // 8
    float* rbuf = (float*)(sm + 2048);                            // 512 f32
    float* pbuf = (float*)(sm + 4096);                            // 2*128 f32
    const int h0 = tid, h1 = tid + 256;
    const int lane = tid & 63;
    const float D0 = 0.90483741803595957316f;
    const float D1 = 0.81873075307798185867f;
    const float DS = 0.81873075307798185867f;
    const float* w0 = Win + (size_t)h0 * NIN;
    const float* w1 = Win + (size_t)h1 * NIN;
    const float* r0 = Wrec + (size_t)h0 * H;
    const float* r1 = Wrec + (size_t)h1 * H;
    float v0 = -60.f, a00 = 0.f, a01 = 0.f, p0 = 0.f, rs0 = 0.f;
    float v1 = -60.f, a10 = 0.f, a11 = 0.f, p1 = 0.f, rs1 = 0.f;
    for (int t = 0; t < TTOT; ++t) {
      __syncthreads();
      xr[tid] = x[((size_t)t * 64 + b) * NIN + tid];
      __syncthreads();
      float xp0 = 0.f, xp1 = 0.f;
#pragma unroll 8
      for (int k = 0; k < NIN; ++k) {
        xp0 += w0[k] * xr[k];
        xp1 += w1[k] * xr[k];
      }
      float vi0 = 0.95f * v0 + 0.5f * (xp0 + p0 + a00 + a01) - 3.0f;
      float vi1 = 0.95f * v1 + 0.5f * (xp1 + p1 + a10 + a11) - 3.0f;
      bool f0 = vi0 >= -45.f, f1 = vi1 >= -45.f;
      unsigned long long b0 = __ballot(f0), b1 = __ballot(f1);
      if (lane == 0) { wbal[wave] = b0; wbal[4 + wave] = b1; }
      __syncthreads();
      float rec0 = 0.f, rec1 = 0.f;
      for (int g = 0; g < 8; ++g) {
        unsigned long long m = wbal[g];
        while (m) {
          int j = (g << 6) + __builtin_ctzll(m);
          m &= m - 1;
          rec0 += r0[j];
          rec1 += r1[j];
        }
      }
      v0 = f0 ? -60.f : vi0;
      v1 = f1 ? -60.f : vi1;
      a00 = a00 * D0 + (f0 ? 1.f : 0.f);
      a01 = a01 * D1 + (f0 ? -2.f : 0.f);
      a10 = a10 * D0 + (f1 ? 1.f : 0.f);
      a11 = a11 * D1 + (f1 ? -2.f : 0.f);
      p0 = p0 * DS + rec0;
      p1 = p1 * DS + rec1;
      rs0 += f0 ? 1.f : 0.f;
      rs1 += f1 ? 1.f : 0.f;
    }
    rbuf[h0] = rs0 * 0.001f;
    rbuf[h1] = rs1 * 0.001f;
    __syncthreads();
    const int o = tid & 127, part = tid >> 7;
    const float4* wr4 = (const float4*)(Wout + (size_t)o * H + part * 256);
    const float* rb = rbuf + part * 256;
    float acc = 0.f;
#pragma unroll 8
    for (int q = 0; q < 64; ++q) {
      float4 wv = wr4[q];
      acc += wv.x * rb[q * 4] + wv.y * rb[q * 4 + 1] + wv.z * rb[q * 4 + 2] +
             wv.w * rb[q * 4 + 3];
    }
    pbuf[part * 128 + o] = acc;
    __syncthreads();
    if (tid < NOUT) out[b * NOUT + tid] = pbuf[tid] + pbuf[128 + tid];
  }
}

extern "C" void kernel_launch(void* const* d_in, const int* in_sizes, int n_in,
                              void* d_out, int out_size, void* d_ws,
                              size_t ws_size, hipStream_t stream) {
  const float* x = (const float*)d_in[0];     // (1000,64,256)
  const float* Win = (const float*)d_in[1];   // (512,256)
  const float* Wrec = (const float*)d_in[2];  // (512,512)
  const float* Wout = (const float*)d_in[3];  // (128,512)
  float* out = (float*)d_out;                 // (64,128)

  char* ws = (char*)d_ws;
  uint8_t* Winb = (uint8_t*)(ws + (1 << 20));      // 128 KB fp8
  int* flags = (int*)(ws + (3 << 19));             // @1.5 MB
  uint8_t* y = (uint8_t*)(ws + (2 << 20));         // 16 MB fp8 @ 2 MB
  float* Bc = (float*)(ws + ((size_t)20 << 20));   // 6.55 MB @ 20 MB
  float* Vst = (float*)(ws + ((size_t)28 << 20));  // 6.55 MB @ 28 MB

  void* args[] = {&x, &Win, &Wrec, &Wout, &out, &y, &Winb, &Bc, &Vst, &flags};
  hipLaunchCooperativeKernel((void*)k_mega, dim3(NBLK), dim3(256), args, 0,
                             stream);
}

// Round 16
// 45.477 us; speedup vs baseline: 6.6166x; 6.6166x over previous
//
#include <hip/hip_runtime.h>
#include <stdint.h>

#define H 512
#define BATCH 64
#define NIN 256
#define NOUT 128
#define TTOT 1000
#define CHL 20
#define NCH 50

typedef __attribute__((ext_vector_type(4))) float f32x4;

// pack 4 f32 -> 4 fp8 e4m3 (OCP) bytes
static __device__ __forceinline__ int pk_fp8x4(float a, float b, float c,
                                               float d) {
  int v = 0;
  v = __builtin_amdgcn_cvt_pk_fp8_f32(a, b, v, false);  // bytes 0,1
  v = __builtin_amdgcn_cvt_pk_fp8_f32(c, d, v, true);   // bytes 2,3
  return v;
}
__device__ __forceinline__ void gload_lds16(const void* g, void* l) {
  __builtin_amdgcn_global_load_lds(
      (const __attribute__((address_space(1))) uint32_t*)g,
      (__attribute__((address_space(3))) uint32_t*)l, 16, 0, 0);
}

// ---- filter (blocks 0..1599) | Win->fp8 cast (1600..1663) ------------------
// y(c,s) = sum_{j<=s} 0.95^(s-j) x(c*20+j), fp8 e4m3 out.
__global__ __launch_bounds__(256) void k_filter(const float* __restrict__ x,
                                                uint8_t* __restrict__ y,
                                                const float* __restrict__ Win,
                                                uint8_t* __restrict__ Winb) {
  const int bid = blockIdx.x;
  const int tid = threadIdx.x;
  if (bid < 1600) {
    __shared__ float4 y9dep[2][64];
    const int c = bid >> 5;             // 50 chunks
    const int bp = bid & 31;            // 32 batch pairs
    const int ig = tid & 63;            // 64 groups of 4 floats
    const int half = (tid >> 6) & 1;    // time half
    const int bo = tid >> 7;            // batch within pair
    const int b = bp * 2 + bo;
    const size_t base = ((size_t)(c * CHL) * 64 + b) * 256 + ig * 4;
    const float* xa = x + base + (size_t)half * 10 * 16384;
    uint8_t* ya = y + base + (size_t)half * 10 * 16384;
    float4 p[10];
    float ax = 0.f, ay = 0.f, az = 0.f, aw = 0.f;
#pragma unroll
    for (int s = 0; s < 10; ++s) {
      float4 xv = *(const float4*)(xa + (size_t)s * 16384);
      ax = 0.95f * ax + xv.x; ay = 0.95f * ay + xv.y;
      az = 0.95f * az + xv.z; aw = 0.95f * aw + xv.w;
      p[s] = make_float4(ax, ay, az, aw);
      if (half == 0)
        *(int*)(ya + (size_t)s * 16384) = pk_fp8x4(ax, ay, az, aw);
    }
    if (half == 0) y9dep[bo][ig] = make_float4(ax, ay, az, aw);
    __syncthreads();
    if (half == 1) {
      const float4 y9 = y9dep[bo][ig];
      const float pw[10] = {0.95f, 0.9025f, 0.857375f, 0.81450625f,
                            0.7737809375f, 0.735091890625f,
                            0.69833729609375f, 0.6634204312890625f,
                            0.6302494097246094f, 0.5987369392383789f};
#pragma unroll
      for (int s = 0; s < 10; ++s) {
        const float ox = p[s].x + pw[s] * y9.x;
        const float oy = p[s].y + pw[s] * y9.y;
        const float oz = p[s].z + pw[s] * y9.z;
        const float ow = p[s].w + pw[s] * y9.w;
        *(int*)(ya + (size_t)s * 16384) = pk_fp8x4(ox, oy, oz, ow);
      }
    }
  } else {
    const int g = (bid - 1600) * 256 + tid;  // 16384 thr x 8 = 512*256
    const float4* ptr = (const float4*)Win + (size_t)g * 2;
    float4 a = ptr[0], b = ptr[1];
    int2 o;
    o.x = pk_fp8x4(a.x, a.y, a.z, a.w);
    o.y = pk_fp8x4(b.x, b.y, b.z, b.w);
    *(int2*)(Winb + (size_t)g * 8) = o;
  }
}

// ---- bc: Bc[(c*64+b), h] = 0.5*(Win . y(c,19)) - 60*(1-a^20)  (f32) --------
__global__ __launch_bounds__(256) void k_bc(const uint8_t* __restrict__ y,
                                            const uint8_t* __restrict__ B,
                                            float* __restrict__ Bc) {
  __shared__ __align__(16) char lds[65536];
  char* ldsA = lds;
  char* ldsB = lds + 32768;
  const int bn = blockIdx.x & 3;   // 4 N-tiles
  const int bm = blockIdx.x >> 2;  // 25 M-tiles (3200 rows)
  const int tid = threadIdx.x;
  const int wave = tid >> 6;
  const int l = tid & 63;
  const int wr = wave >> 1, wc = wave & 1;
  const int fr = l & 15, fq = l >> 4;
  const char* Bb = (const char*)B + (size_t)bn * 128 * 256;
  const int scol = (l & 15) * 16;
#pragma unroll
  for (int i = 0; i < 8; ++i) {
    const int r0 = wave * 32 + i * 4;
    const int r = r0 + (l >> 4);
    const int sc = scol ^ ((r & 7) << 4);
    const int vr = bm * 128 + r;  // virtual row -> (chunk, batch)
    const int cc = vr >> 6, bb2 = vr & 63;
    gload_lds16((const char*)y + ((size_t)(cc * CHL + CHL - 1) * 64 + bb2) * 256 + sc,
                ldsA + r0 * 256);
    gload_lds16(Bb + (size_t)r * 256 + sc, ldsB + r0 * 256);
  }
  __syncthreads();
  f32x4 acc[4][4] = {};
#pragma unroll
  for (int kk = 0; kk < 8; ++kk) {
    const int cb = kk * 32 + fq * 8;
    long a[4], b[4];
#pragma unroll
    for (int m = 0; m < 4; ++m) {
      const int row = wr * 64 + m * 16 + fr;
      a[m] = *(const long*)(ldsA + row * 256 + (cb ^ ((row & 7) << 4)));
    }
#pragma unroll
    for (int n = 0; n < 4; ++n) {
      const int row = wc * 64 + n * 16 + fr;
      b[n] = *(const long*)(ldsB + row * 256 + (cb ^ ((row & 7) << 4)));
    }
#pragma unroll
    for (int m = 0; m < 4; ++m)
#pragma unroll
      for (int n = 0; n < 4; ++n)
        acc[m][n] = __builtin_amdgcn_mfma_f32_16x16x32_fp8_fp8(a[m], b[n],
                                                               acc[m][n], 0, 0, 0);
  }
#pragma unroll
  for (int m = 0; m < 4; ++m) {
    const int r0 = bm * 128 + wr * 64 + m * 16 + fq * 4;
#pragma unroll
    for (int n = 0; n < 4; ++n) {
      const int col = bn * 128 + wc * 64 + n * 16 + fr;
      f32x4 a = acc[m][n];
#pragma unroll
      for (int j = 0; j < 4; ++j)
        Bc[(size_t)(r0 + j) * 512 + col] = 0.5f * a[j] - 38.4908446554876f;
    }
  }
}

// ---- compose: Vst[c] = v0 before chunk c; block 128 zero-fills out ---------
__global__ __launch_bounds__(256) void k_compose(const float* __restrict__ Bc,
                                                 float* __restrict__ Vst,
                                                 int* __restrict__ flags,
                                                 float* __restrict__ out) {
  if (blockIdx.x == 128) {  // zero out (64x128 floats = 2048 float4)
    float4 z = make_float4(0.f, 0.f, 0.f, 0.f);
    float4* o = (float4*)out + threadIdx.x;
#pragma unroll
    for (int i = 0; i < 8; ++i) o[i * 256] = z;
    return;
  }
  if (blockIdx.x == 0 && threadIdx.x < BATCH) flags[threadIdx.x] = 0;
  const int idx = blockIdx.x * 256 + threadIdx.x;  // 32768 = 64b*512h
  const float AL = 0.35848592240854223f;           // 0.95^20
  float v = -60.f;
#pragma unroll
  for (int c = 0; c < NCH; c += 5) {
    float b0 = Bc[(size_t)(c + 0) * 32768 + idx];
    float b1 = Bc[(size_t)(c + 1) * 32768 + idx];
    float b2 = Bc[(size_t)(c + 2) * 32768 + idx];
    float b3 = Bc[(size_t)(c + 3) * 32768 + idx];
    float b4 = Bc[(size_t)(c + 4) * 32768 + idx];
    Vst[(size_t)(c + 0) * 32768 + idx] = v; v = AL * v + b0;
    Vst[(size_t)(c + 1) * 32768 + idx] = v; v = AL * v + b1;
    Vst[(size_t)(c + 2) * 32768 + idx] = v; v = AL * v + b2;
    Vst[(size_t)(c + 3) * 32768 + idx] = v; v = AL * v + b3;
    Vst[(size_t)(c + 4) * 32768 + idx] = v; v = AL * v + b4;
  }
}

// ---- screen: fp8 GEMM y.Win^T, BK=128, T14 reg prefetch, FULLY INLINE ------
// Rounds 11-13 regression root-cause: mfma helper with f32x4 acc[4][4] array
// parameter -> address taken -> scratch (32KB/block spill). All loops inline
// here, staging in NAMED float4 scalars.
// v(t) = a^(s+1)*(v0+60) + 0.5*acc - 60 >= -45.5 <=> acc >= 29 - 2*As*(v0+60)
__global__ __launch_bounds__(256, 2) void k_screen(
    const uint8_t* __restrict__ A, const uint8_t* __restrict__ B,
    const float* __restrict__ Vst, int* __restrict__ flags) {
  __shared__ __align__(16) char lds[32768];
  char* ldsA = lds;            // 128 rows x 128 B
  char* ldsB = lds + 16384;    // 128 rows x 128 B
  const int bid = blockIdx.x;
  const int wg = (bid & 7) * 250 + (bid >> 3);  // XCD swizzle, 2000%8==0
  const int bn = wg & 3;
  const int bm = wg >> 2;  // 500 M-tiles
  const int tid = threadIdx.x;
  const int wave = tid >> 6;
  const int l = tid & 63;
  const int wr = wave >> 1, wc = wave & 1;
  const int fr = l & 15, fq = l >> 4;
  const char* Ab = (const char*)A + (size_t)bm * 128 * 256;
  const char* Bb = (const char*)B + (size_t)bn * 128 * 256;
  // stage-lane geometry: 64 lanes x 16B = 1 KB = 8 rows of 128 B
  const int srow = l >> 3;                       // row within 8-row chunk
  const int scol = (((l & 7) ^ srow) << 4);      // inverse-swizzled source col

  // ---- stage 0: direct global -> LDS (kb = 0) ----
#pragma unroll
  for (int i = 0; i < 4; ++i) {
    const int q = wave * 4 + i;  // 16 chunks of 8 rows
    const int row = q * 8 + srow;
    gload_lds16(Ab + (size_t)row * 256 + scol, ldsA + q * 1024);
    gload_lds16(Bb + (size_t)row * 256 + scol, ldsB + q * 1024);
  }
  __syncthreads();  // stage 0 resident
  // ---- issue stage 1 (kb=128) into NAMED regs; hides under stage-0 MFMA ----
  const char* Ab1 = Ab + (size_t)(wave * 32 + srow) * 256 + 128 + scol;
  const char* Bb1 = Bb + (size_t)(wave * 32 + srow) * 256 + 128 + scol;
  float4 sa0 = *(const float4*)(Ab1);
  float4 sa1 = *(const float4*)(Ab1 + 8 * 256);
  float4 sa2 = *(const float4*)(Ab1 + 16 * 256);
  float4 sa3 = *(const float4*)(Ab1 + 24 * 256);
  float4 sb0 = *(const float4*)(Bb1);
  float4 sb1 = *(const float4*)(Bb1 + 8 * 256);
  float4 sb2 = *(const float4*)(Bb1 + 16 * 256);
  float4 sb3 = *(const float4*)(Bb1 + 24 * 256);
  // ---- stage 0 compute: 4 kk x {8 ds_read_b64 + 16 MFMA} (inline) ----
  f32x4 acc[4][4] = {};
#pragma unroll
  for (int kk = 0; kk < 4; ++kk) {
    const int cb = kk * 32 + fq * 8;
    long a[4], b[4];
#pragma unroll
    for (int m = 0; m < 4; ++m) {
      const int row = wr * 64 + m * 16 + fr;
      a[m] = *(const long*)(ldsA + row * 128 + (cb ^ ((row & 7) << 4)));
    }
#pragma unroll
    for (int n = 0; n < 4; ++n) {
      const int row = wc * 64 + n * 16 + fr;
      b[n] = *(const long*)(ldsB + row * 128 + (cb ^ ((row & 7) << 4)));
    }
#pragma unroll
    for (int m = 0; m < 4; ++m)
#pragma unroll
      for (int n = 0; n < 4; ++n)
        acc[m][n] = __builtin_amdgcn_mfma_f32_16x16x32_fp8_fp8(a[m], b[n],
                                                               acc[m][n], 0, 0, 0);
  }
  __syncthreads();  // all waves done reading stage-0 LDS
  // ---- stage 1: regs -> LDS (linear, same layout as gload path) ----
  *(float4*)(ldsA + (wave * 4 + 0) * 1024 + l * 16) = sa0;
  *(float4*)(ldsA + (wave * 4 + 1) * 1024 + l * 16) = sa1;
  *(float4*)(ldsA + (wave * 4 + 2) * 1024 + l * 16) = sa2;
  *(float4*)(ldsA + (wave * 4 + 3) * 1024 + l * 16) = sa3;
  *(float4*)(ldsB + (wave * 4 + 0) * 1024 + l * 16) = sb0;
  *(float4*)(ldsB + (wave * 4 + 1) * 1024 + l * 16) = sb1;
  *(float4*)(ldsB + (wave * 4 + 2) * 1024 + l * 16) = sb2;
  *(float4*)(ldsB + (wave * 4 + 3) * 1024 + l * 16) = sb3;
  __syncthreads();
  // ---- stage 1 compute (inline, identical loop) ----
#pragma unroll
  for (int kk = 0; kk < 4; ++kk) {
    const int cb = kk * 32 + fq * 8;
    long a[4], b[4];
#pragma unroll
    for (int m = 0; m < 4; ++m) {
      const int row = wr * 64 + m * 16 + fr;
      a[m] = *(const long*)(ldsA + row * 128 + (cb ^ ((row & 7) << 4)));
    }
#pragma unroll
    for (int n = 0; n < 4; ++n) {
      const int row = wc * 64 + n * 16 + fr;
      b[n] = *(const long*)(ldsB + row * 128 + (cb ^ ((row & 7) << 4)));
    }
#pragma unroll
    for (int m = 0; m < 4; ++m)
#pragma unroll
      for (int n = 0; n < 4; ++n)
        acc[m][n] = __builtin_amdgcn_mfma_f32_16x16x32_fp8_fp8(a[m], b[n],
                                                               acc[m][n], 0, 0, 0);
  }
  __syncthreads();
  // ---- epilogue: stage block-uniform Vst slice (64 b x 128 h = 32 KB) ------
  const int c = (bm * 2) / CHL;           // block-uniform (CHL even)
  const int s = (bm * 2 + wr) - c * CHL;  // wave-uniform step within chunk
  float* ldsV = (float*)lds;              // full 32 KB now free
  {
    const float* vsrc = Vst + ((size_t)c * 64) * 512 + bn * 128;
    const int vrow = l >> 5;
    const int vcol = (l & 31) * 4;  // floats
#pragma unroll
    for (int i = 0; i < 8; ++i) {
      const int brow = (wave * 8 + i) * 2 + vrow;
      gload_lds16(vsrc + (size_t)brow * 512 + vcol, ldsV + (wave * 8 + i) * 256);
    }
  }
  __syncthreads();
  const float As = exp2f(-(float)(s + 1) * 0.07400058144086257f);  // .95^(s+1)
  unsigned int cmask = 0;
#pragma unroll
  for (int m = 0; m < 4; ++m) {
#pragma unroll
    for (int j = 0; j < 4; ++j) {
      const int b = m * 16 + fq * 4 + j;
      bool cb2 = false;
#pragma unroll
      for (int n = 0; n < 4; ++n) {
        const int hl = wc * 64 + n * 16 + fr;
        const float th = 29.f - 2.f * As * (ldsV[b * 128 + hl] + 60.f);
        cb2 |= (acc[m][n][j] >= th);
      }
      cmask |= cb2 ? (1u << (m * 4 + j)) : 0u;
    }
  }
  if (__ballot(cmask != 0u)) {  // never taken when no membrane nears threshold
#pragma unroll
    for (int m = 0; m < 4; ++m)
#pragma unroll
      for (int j = 0; j < 4; ++j)
        if (cmask & (1u << (m * 4 + j))) flags[m * 16 + fq * 4 + j] = 1;
  }
}

// ---- fallback: exact f32 sequential sim; pure early-exit when clean --------
__global__ __launch_bounds__(512) void k_fallback(
    const float* __restrict__ x, const float* __restrict__ Win,
    const float* __restrict__ Wrec, const float* __restrict__ Wout,
    const int* __restrict__ flags, float* __restrict__ out) {
  const int b = blockIdx.x;
  const int h = threadIdx.x;
  if (!flags[b]) return;  // out already zero-filled by k_compose
  const int wid = h >> 6;
  const int lane = h & 63;
  __shared__ float xr[NIN];
  __shared__ unsigned long long wbal[8];
  __shared__ float rbuf[H];
  __shared__ float pbuf[4][NOUT];
  const float D0 = 0.90483741803595957316f;
  const float D1 = 0.81873075307798185867f;
  const float DS = 0.81873075307798185867f;
  const float* wrow = Win + (size_t)h * NIN;
  const float* rrow = Wrec + (size_t)h * H;
  float v = -60.f, a0 = 0.f, a1 = 0.f, psc = 0.f, rsum = 0.f;
  for (int t = 0; t < TTOT; ++t) {
    __syncthreads();
    if (h < NIN) xr[h] = x[((size_t)t * 64 + b) * NIN + h];
    __syncthreads();
    float xp = 0.f;
#pragma unroll 8
    for (int k = 0; k < NIN; ++k) xp += wrow[k] * xr[k];
    float It = xp + psc + a0 + a1;
    float vint = 0.95f * v + 0.5f * It - 3.0f;
    bool fire = vint >= -45.f;
    unsigned long long bal = __ballot(fire);
    if (lane == 0) wbal[wid] = bal;
    __syncthreads();
    float rec = 0.f;
    for (int g = 0; g < 8; ++g) {
      unsigned long long m = wbal[g];
      while (m) {
        int j = (g << 6) + __builtin_ctzll(m);
        m &= m - 1;
        rec += rrow[j];
      }
    }
    v = fire ? -60.f : vint;
    a0 = a0 * D0 + (fire ? 1.f : 0.f);
    a1 = a1 * D1 + (fire ? -2.f : 0.f);
    psc = psc * DS + rec;
    rsum += fire ? 1.f : 0.f;
  }
  rbuf[h] = rsum * 0.001f;
  __syncthreads();
  const int o = h & 127, part = h >> 7;
  const float4* wr4 = (const float4*)(Wout + (size_t)o * H + part * 128);
  const float* rb = rbuf + part * 128;
  float acc = 0.f;
#pragma unroll 8
  for (int q = 0; q < 32; ++q) {
    float4 wv = wr4[q];
    acc += wv.x * rb[q * 4] + wv.y * rb[q * 4 + 1] + wv.z * rb[q * 4 + 2] +
           wv.w * rb[q * 4 + 3];
  }
  pbuf[part][o] = acc;
  __syncthreads();
  if (h < NOUT)
    out[b * NOUT + h] = pbuf[0][h] + pbuf[1][h] + pbuf[2][h] + pbuf[3][h];
}

extern "C" void kernel_launch(void* const* d_in, const int* in_sizes, int n_in,
                              void* d_out, int out_size, void* d_ws,
                              size_t ws_size, hipStream_t stream) {
  const float* x = (const float*)d_in[0];     // (1000,64,256)
  const float* Win = (const float*)d_in[1];   // (512,256)
  const float* Wrec = (const float*)d_in[2];  // (512,512)
  const float* Wout = (const float*)d_in[3];  // (128,512)
  float* out = (float*)d_out;                 // (64,128)

  char* ws = (char*)d_ws;
  uint8_t* Winb = (uint8_t*)(ws + (1 << 20));      // 128 KB fp8
  int* flags = (int*)(ws + (3 << 19));             // @1.5 MB
  uint8_t* y = (uint8_t*)(ws + (2 << 20));         // 16 MB fp8 @ 2 MB
  float* Bc = (float*)(ws + ((size_t)20 << 20));   // 6.55 MB @ 20 MB
  float* Vst = (float*)(ws + ((size_t)28 << 20));  // 6.55 MB @ 28 MB

  hipLaunchKernelGGL(k_filter, dim3(1664), dim3(256), 0, stream, x, y, Win,
                     Winb);
  hipLaunchKernelGGL(k_bc, dim3(100), dim3(256), 0, stream, y, Winb, Bc);
  hipLaunchKernelGGL(k_compose, dim3(129), dim3(256), 0, stream, Bc, Vst,
                     flags, out);
  hipLaunchKernelGGL(k_screen, dim3(2000), dim3(256), 0, stream, y, Winb, Vst,
                     flags);
  hipLaunchKernelGGL(k_fallback, dim3(BATCH), dim3(512), 0, stream, x, Win,
                     Wrec, Wout, flags, out);
}